// Round 2
// baseline (133.230 us; speedup 1.0000x reference)
//
#include <hip/hip_runtime.h>
#include <hip/hip_bf16.h>

// Problem constants
#define HDIM 512
#define NVAR 32
#define LAGD 1024
#define BATCH 256
#define MDIM 1024
#define SPLIT 16   // split-K for mlp1 (K slice = 1024)

typedef __attribute__((ext_vector_type(4))) float f32x4;
typedef __attribute__((ext_vector_type(8))) short short8;
typedef __attribute__((ext_vector_type(4))) unsigned short us4;
typedef __attribute__((ext_vector_type(8))) unsigned short us8;

__device__ __forceinline__ unsigned short f2bf(float f) {
  union { __hip_bfloat16 b; unsigned short s; } cv;
  cv.b = __float2bfloat16(f);     // compiles to v_cvt_pk_bf16_f32 (RNE)
  return cv.s;
}
__device__ __forceinline__ float bf2f(unsigned short s) {
  union { unsigned u; float f; } x; x.u = ((unsigned)s) << 16;
  return x.f;
}
__device__ __forceinline__ us4 cvt4(f32x4 d) {
  us4 u;
#pragma unroll
  for (int e = 0; e < 4; ++e) u[e] = f2bf(d[e]);
  return u;
}

// ---------------------------------------------------------------------------
// K1: fused gates GEMM + LSTM-cell activation.
//   For variable v, h-tile [h0,h0+64):
//     i[m][h] = sum_k X[m][v][k] * W[v][h][k]
//     g[m][h] = sum_k X[m][v][k] * W[v][1024+h][k]
//     agg[m][v*512+h] = bf16( sigmoid(i+bi) * tanh(g+bg) * imp[v] )
//   BM=256 (whole batch -> W fetched exactly once), BK=64, 8 waves.
//   Wave (wm 0..3, wh 0..1): 64 m-rows x 32 h-cols, dual acc (i and g).
// ---------------------------------------------------------------------------
__global__ __launch_bounds__(512) void k1_gates_fused(
    const float* __restrict__ X,     // [BATCH][NVAR][LAGD]
    const float* __restrict__ W,     // [NVAR][2048][LAGD]
    const float* __restrict__ b_ih,  // [NVAR][2048]
    const float* __restrict__ b_hh,  // [NVAR][2048]
    const float* __restrict__ imp,   // [NVAR]
    unsigned short* __restrict__ agg)// [BATCH][NVAR*HDIM] bf16
{
  const int v  = blockIdx.z;
  const int h0 = blockIdx.x * 64;
  const int t    = threadIdx.x;
  const int lane = t & 63;
  const int wv   = t >> 6;
  const int wm   = wv & 3;   // m quarter (64 rows)
  const int wh   = wv >> 2;  // h half (32 cols)

  __shared__ unsigned short As[256][72];  // +8 pad -> 2-way banks (free)
  __shared__ unsigned short Bi[64][72];
  __shared__ unsigned short Bg[64][72];

  f32x4 acc_i[4][2] = {};
  f32x4 acc_g[4][2] = {};

  const int srow = t >> 4;          // 0..31
  const int scol = (t & 15) << 2;   // 0,4,...,60

  const float* Xv = X + (size_t)v * LAGD;
  const float* Wv = W + (size_t)v * 2048 * LAGD;

  for (int k0 = 0; k0 < LAGD; k0 += 64) {
    // stage A: X tile 256 x 64, fp32 -> bf16
#pragma unroll
    for (int p = 0; p < 8; ++p) {
      int r = (p << 5) + srow;
      f32x4 d = *(const f32x4*)(Xv + (size_t)r * (NVAR * LAGD) + k0 + scol);
      *(us4*)&As[r][scol] = cvt4(d);
    }
    // stage Bi: W rows h0..h0+63 (i gate)
#pragma unroll
    for (int p = 0; p < 2; ++p) {
      int r = (p << 5) + srow;
      f32x4 d = *(const f32x4*)(Wv + (size_t)(h0 + r) * LAGD + k0 + scol);
      *(us4*)&Bi[r][scol] = cvt4(d);
    }
    // stage Bg: W rows 1024+h0.. (g gate)
#pragma unroll
    for (int p = 0; p < 2; ++p) {
      int r = (p << 5) + srow;
      f32x4 d = *(const f32x4*)(Wv + (size_t)(1024 + h0 + r) * LAGD + k0 + scol);
      *(us4*)&Bg[r][scol] = cvt4(d);
    }
    __syncthreads();

    const int fr = lane & 15;
    const int kc = (lane >> 4) << 3;   // 0,8,16,24
#pragma unroll
    for (int kk = 0; kk < 2; ++kk) {
      short8 a[4], fi[2], fg[2];
#pragma unroll
      for (int i = 0; i < 4; ++i)
        a[i] = *(const short8*)&As[(wm << 6) + (i << 4) + fr][(kk << 5) + kc];
#pragma unroll
      for (int j = 0; j < 2; ++j) {
        fi[j] = *(const short8*)&Bi[(wh << 5) + (j << 4) + fr][(kk << 5) + kc];
        fg[j] = *(const short8*)&Bg[(wh << 5) + (j << 4) + fr][(kk << 5) + kc];
      }
#pragma unroll
      for (int i = 0; i < 4; ++i)
#pragma unroll
        for (int j = 0; j < 2; ++j) {
          acc_i[i][j] = __builtin_amdgcn_mfma_f32_16x16x32_bf16(a[i], fi[j], acc_i[i][j], 0, 0, 0);
          acc_g[i][j] = __builtin_amdgcn_mfma_f32_16x16x32_bf16(a[i], fg[j], acc_g[i][j], 0, 0, 0);
        }
    }
    __syncthreads();
  }

  // fused epilogue: c = sigmoid(i+bi)*tanh(g+bg)*imp -> agg bf16
  const int col16 = lane & 15;
  const int row4  = (lane >> 4) << 2;
  const float impv = imp[v];
#pragma unroll
  for (int j = 0; j < 2; ++j) {
    const int h = h0 + (wh << 5) + (j << 4) + col16;
    const float bsi = b_ih[v * 2048 + h] + b_hh[v * 2048 + h];
    const float bsg = b_ih[v * 2048 + 1024 + h] + b_hh[v * 2048 + 1024 + h];
#pragma unroll
    for (int i = 0; i < 4; ++i)
#pragma unroll
      for (int r = 0; r < 4; ++r) {
        const int m = (wm << 6) + (i << 4) + row4 + r;
        const float ii = acc_i[i][j][r] + bsi;
        const float gg = acc_g[i][j][r] + bsg;
        const float sig = 1.0f / (1.0f + __expf(-ii));
        const float c = sig * tanhf(gg) * impv;
        agg[(size_t)m * (NVAR * HDIM) + v * HDIM + h] = f2bf(c);
      }
  }
}

// ---------------------------------------------------------------------------
// K3: mlp1 split-K GEMM.  part[s][m][n] = sum_{k in slice s} agg[m][k]*W1[n][k]
//   BM=256 (W1 fetched once), BN=64, Kslice=1024, BK=64, 8 waves.
// ---------------------------------------------------------------------------
__global__ __launch_bounds__(512) void k3_mlp1(
    const unsigned short* __restrict__ A,  // agg [BATCH][16384] bf16
    const float* __restrict__ Wm,          // [1024][16384] fp32
    float* __restrict__ part)              // [SPLIT][BATCH][1024]
{
  const int s  = blockIdx.z;
  const int n0 = blockIdx.x * 64;
  const int t    = threadIdx.x;
  const int lane = t & 63;
  const int wv   = t >> 6;
  const int wm   = wv & 3;
  const int wn   = wv >> 2;

  __shared__ unsigned short As[256][72];
  __shared__ unsigned short Bs[64][72];

  f32x4 acc[4][2] = {};

  const int kbase = s * 1024;

  for (int k0 = 0; k0 < 1024; k0 += 64) {
    // stage A: 256 x 64 bf16 (direct copy, us8)
#pragma unroll
    for (int p = 0; p < 4; ++p) {
      int r = (p << 6) + (t >> 3);
      int c = (t & 7) << 3;
      *(us8*)&As[r][c] = *(const us8*)(A + (size_t)r * 16384 + kbase + k0 + c);
    }
    // stage B: W1 rows n0..n0+63, fp32 -> bf16
#pragma unroll
    for (int p = 0; p < 2; ++p) {
      int r = (p << 5) + (t >> 4);
      int c = (t & 15) << 2;
      f32x4 d = *(const f32x4*)(Wm + (size_t)(n0 + r) * 16384 + kbase + k0 + c);
      *(us4*)&Bs[r][c] = cvt4(d);
    }
    __syncthreads();

    const int fr = lane & 15;
    const int kc = (lane >> 4) << 3;
#pragma unroll
    for (int kk = 0; kk < 2; ++kk) {
      short8 a[4], b[2];
#pragma unroll
      for (int i = 0; i < 4; ++i)
        a[i] = *(const short8*)&As[(wm << 6) + (i << 4) + fr][(kk << 5) + kc];
#pragma unroll
      for (int j = 0; j < 2; ++j)
        b[j] = *(const short8*)&Bs[(wn << 5) + (j << 4) + fr][(kk << 5) + kc];
#pragma unroll
      for (int i = 0; i < 4; ++i)
#pragma unroll
        for (int j = 0; j < 2; ++j)
          acc[i][j] = __builtin_amdgcn_mfma_f32_16x16x32_bf16(a[i], b[j], acc[i][j], 0, 0, 0);
    }
    __syncthreads();
  }

  const int col16 = lane & 15;
  const int row4  = (lane >> 4) << 2;
  float* outp = part + (size_t)s * BATCH * 1024;
#pragma unroll
  for (int i = 0; i < 4; ++i)
#pragma unroll
    for (int j = 0; j < 2; ++j)
#pragma unroll
      for (int r = 0; r < 4; ++r) {
        const int m = (wm << 6) + (i << 4) + row4 + r;
        const int n = n0 + (wn << 5) + (j << 4) + col16;
        outp[(size_t)m * 1024 + n] = acc[i][j][r];
      }
}

// ---------------------------------------------------------------------------
// K4: reduce split-K partials + bias + relu -> hid bf16 [BATCH][1024]
// ---------------------------------------------------------------------------
__global__ __launch_bounds__(256) void k4_reduce(
    const float* __restrict__ part,   // [SPLIT][BATCH][1024]
    const float* __restrict__ b1,     // [1024]
    unsigned short* __restrict__ hid) // [BATCH][1024] bf16
{
  const int idx = blockIdx.x * 256 + threadIdx.x;  // BATCH*1024
  const int n = idx & 1023;
  float s = b1[n];
#pragma unroll
  for (int t = 0; t < SPLIT; ++t)
    s += part[(size_t)t * BATCH * 1024 + idx];
  s = fmaxf(s, 0.0f);
  hid[idx] = f2bf(s);
}

// ---------------------------------------------------------------------------
// K5: mlp2.  out[b] = b2 + sum_n hid[b][n]*w2[n].  One wave per row.
// ---------------------------------------------------------------------------
__global__ __launch_bounds__(256) void k5_mlp2(
    const unsigned short* __restrict__ hid,  // [BATCH][1024] bf16
    const float* __restrict__ w2,            // [1024]
    const float* __restrict__ b2,            // [1]
    float* __restrict__ out)                 // [BATCH]
{
  const int b    = blockIdx.x * 4 + (threadIdx.x >> 6);
  const int lane = threadIdx.x & 63;
  float s = 0.0f;
#pragma unroll
  for (int n = lane; n < 1024; n += 64)
    s += bf2f(hid[b * 1024 + n]) * w2[n];
#pragma unroll
  for (int off = 32; off > 0; off >>= 1)
    s += __shfl_down(s, off);
  if (lane == 0) out[b] = s + b2[0];
}

// ---------------------------------------------------------------------------
extern "C" void kernel_launch(void* const* d_in, const int* in_sizes, int n_in,
                              void* d_out, int out_size, void* d_ws, size_t ws_size,
                              hipStream_t stream) {
  const float* inputs = (const float*)d_in[0];
  const float* W_ih   = (const float*)d_in[1];
  // d_in[2] = W_hh: unused (h0 == 0)
  const float* b_ih   = (const float*)d_in[3];
  const float* b_hh   = (const float*)d_in[4];
  const float* imp    = (const float*)d_in[5];
  const float* m1w    = (const float*)d_in[6];
  const float* m1b    = (const float*)d_in[7];
  const float* m2w    = (const float*)d_in[8];
  const float* m2b    = (const float*)d_in[9];
  float* out = (float*)d_out;

  char* ws = (char*)d_ws;
  unsigned short* agg = (unsigned short*)ws;                 // 8 MB [256][16384] bf16
  float* part         = (float*)(ws + (8u << 20));           // 16 MB [16][256][1024] f32
  unsigned short* hid = (unsigned short*)(ws + (24u << 20)); // 0.5 MB [256][1024] bf16

  k1_gates_fused<<<dim3(8, 1, 32), 512, 0, stream>>>(inputs, W_ih, b_ih, b_hh, imp, agg);
  k3_mlp1       <<<dim3(16, 1, SPLIT), 512, 0, stream>>>(agg, m1w, part);
  k4_reduce     <<<dim3(1024), 256, 0, stream>>>(part, m1b, hid);
  k5_mlp2       <<<dim3(64), 256, 0, stream>>>(hid, m2w, m2b, out);
}

// Round 3
// 103.008 us; speedup vs baseline: 1.2934x; 1.2934x over previous
//
#include <hip/hip_runtime.h>
#include <hip/hip_bf16.h>

// Problem constants
#define HDIM 512
#define NVAR 32
#define LAGD 1024
#define BATCH 256
#define SPLIT 32   // split-K for mlp1 (K slice = 512)

typedef __attribute__((ext_vector_type(4))) float f32x4;
typedef __attribute__((ext_vector_type(8))) short short8;
typedef __attribute__((ext_vector_type(4))) unsigned short us4;
typedef __attribute__((ext_vector_type(8))) unsigned short us8;

__device__ __forceinline__ unsigned short f2bf(float f) {
  union { __hip_bfloat16 b; unsigned short s; } cv;
  cv.b = __float2bfloat16(f);
  return cv.s;
}
__device__ __forceinline__ float bf2f(unsigned short s) {
  union { unsigned u; float f; } x; x.u = ((unsigned)s) << 16;
  return x.f;
}
__device__ __forceinline__ us4 cvt4(f32x4 d) {
  us4 u;
#pragma unroll
  for (int e = 0; e < 4; ++e) u[e] = f2bf(d[e]);
  return u;
}

// Barrier that does NOT drain vmcnt (in-flight global prefetch survives).
// LDS ordering needs lgkmcnt(0) only; "memory" clobber pins C++ mem ops.
__device__ __forceinline__ void sync_ds() {
  asm volatile("s_waitcnt lgkmcnt(0)" ::: "memory");
  __builtin_amdgcn_s_barrier();
}

// ---------------------------------------------------------------------------
// K1: fused gates GEMM + LSTM activation.
//   Block = (var v, h-tile of 32). BM=256 (whole batch), BK=64, 512 thr.
//   W fetched exactly once (h-tiles partition W rows). Reg-prefetch pipeline.
//   XCD swizzle: each XCD owns 4 consecutive vars (X slice stays in its L2).
// ---------------------------------------------------------------------------
__global__ __launch_bounds__(512, 4) void k1_gates_fused(
    const float* __restrict__ X,     // [BATCH][NVAR][LAGD]
    const float* __restrict__ W,     // [NVAR][2048][LAGD]
    const float* __restrict__ b_ih,  // [NVAR][2048]
    const float* __restrict__ b_hh,  // [NVAR][2048]
    const float* __restrict__ imp,   // [NVAR]
    unsigned short* __restrict__ agg)// [BATCH][NVAR*HDIM] bf16
{
  const int bid   = blockIdx.x;                 // 0..511
  const int chunk = ((bid & 7) << 6) | (bid >> 3);  // XCD-contiguous
  const int v  = chunk >> 4;
  const int h0 = (chunk & 15) << 5;             // 0,32,...,480

  const int t    = threadIdx.x;
  const int lane = t & 63;
  const int wv   = t >> 6;
  const int wm   = wv & 3;    // 64 m-rows per wave
  const int wh   = wv >> 2;   // 16 h-cols per wave

  __shared__ unsigned short As[256][72];  // pad 72 -> 2-way banks (free)
  __shared__ unsigned short Bi[32][72];
  __shared__ unsigned short Bg[32][72];

  f32x4 acc_i[4] = {};
  f32x4 acc_g[4] = {};

  const int srow = t >> 4;          // 0..31
  const int scol = (t & 15) << 2;   // 0..60

  const float* Xs = X + (size_t)v * LAGD + (size_t)srow * (NVAR * LAGD) + scol;
  const float* Wv = W + (size_t)v * 2048 * LAGD;
  const float* Wi = Wv + (size_t)(h0 + srow) * LAGD + scol;
  const float* Wg = Wv + (size_t)(1024 + h0 + srow) * LAGD + scol;

  f32x4 pa[8], pbi, pbg;

#define K1_LOAD(k0) do {                                                      \
    _Pragma("unroll")                                                         \
    for (int p = 0; p < 8; ++p)                                               \
      pa[p] = *(const f32x4*)(Xs + (size_t)(p << 5) * (NVAR * LAGD) + (k0));  \
    pbi = *(const f32x4*)(Wi + (k0));                                         \
    pbg = *(const f32x4*)(Wg + (k0));                                         \
  } while (0)

#define K1_WRITE() do {                                                       \
    _Pragma("unroll")                                                         \
    for (int p = 0; p < 8; ++p)                                               \
      *(us4*)&As[(p << 5) + srow][scol] = cvt4(pa[p]);                        \
    *(us4*)&Bi[srow][scol] = cvt4(pbi);                                       \
    *(us4*)&Bg[srow][scol] = cvt4(pbg);                                       \
  } while (0)

#define K1_COMPUTE() do {                                                     \
    const int fr = lane & 15;                                                 \
    const int kc = (lane >> 4) << 3;                                          \
    _Pragma("unroll")                                                         \
    for (int kk = 0; kk < 2; ++kk) {                                          \
      short8 a[4], fi, fg;                                                    \
      _Pragma("unroll")                                                       \
      for (int i = 0; i < 4; ++i)                                             \
        a[i] = *(const short8*)&As[(wm << 6) + (i << 4) + fr][(kk << 5) + kc];\
      fi = *(const short8*)&Bi[(wh << 4) + fr][(kk << 5) + kc];               \
      fg = *(const short8*)&Bg[(wh << 4) + fr][(kk << 5) + kc];               \
      _Pragma("unroll")                                                       \
      for (int i = 0; i < 4; ++i) {                                           \
        acc_i[i] = __builtin_amdgcn_mfma_f32_16x16x32_bf16(a[i], fi, acc_i[i], 0, 0, 0); \
        acc_g[i] = __builtin_amdgcn_mfma_f32_16x16x32_bf16(a[i], fg, acc_g[i], 0, 0, 0); \
      }                                                                       \
    }                                                                         \
  } while (0)

  K1_LOAD(0);
  K1_WRITE();
  sync_ds();
  for (int k0 = 64; k0 < 1024; k0 += 64) {
    K1_LOAD(k0);      // issue next tile's loads (latency hides under compute)
    K1_COMPUTE();     // current tile from LDS
    sync_ds();        // all reads done
    K1_WRITE();       // vmcnt waits land here
    sync_ds();        // writes visible
  }
  K1_COMPUTE();

  // fused epilogue: c = sigmoid(i+bi)*tanh(g+bg)*imp -> agg bf16
  const int col16 = lane & 15;
  const int row4  = (lane >> 4) << 2;
  const float impv = imp[v];
  const int h = h0 + (wh << 4) + col16;
  const float bsi = b_ih[v * 2048 + h] + b_hh[v * 2048 + h];
  const float bsg = b_ih[v * 2048 + 1024 + h] + b_hh[v * 2048 + 1024 + h];
#pragma unroll
  for (int i = 0; i < 4; ++i)
#pragma unroll
    for (int r = 0; r < 4; ++r) {
      const int m = (wm << 6) + (i << 4) + row4 + r;
      const float ii = acc_i[i][r] + bsi;
      const float gg = acc_g[i][r] + bsg;
      const float c = (1.0f / (1.0f + __expf(-ii))) * tanhf(gg) * impv;
      agg[(size_t)m * (NVAR * HDIM) + v * HDIM + h] = f2bf(c);
    }
#undef K1_LOAD
#undef K1_WRITE
#undef K1_COMPUTE
}

// ---------------------------------------------------------------------------
// K3: mlp1 split-K GEMM. Block = (split s of 512 k, n-tile of 64).
//   BM=256, BK=64, 512 thr, same prefetch pipeline. XCD owns 4 splits.
// ---------------------------------------------------------------------------
__global__ __launch_bounds__(512, 4) void k3_mlp1(
    const unsigned short* __restrict__ A,  // agg [BATCH][16384] bf16
    const float* __restrict__ Wm,          // [1024][16384] fp32
    float* __restrict__ part)              // [SPLIT][BATCH][1024]
{
  const int bid   = blockIdx.x;                 // 0..511
  const int chunk = ((bid & 7) << 6) | (bid >> 3);
  const int s  = chunk >> 4;                    // 0..31
  const int n0 = (chunk & 15) << 6;             // 0..960

  const int t    = threadIdx.x;
  const int lane = t & 63;
  const int wv   = t >> 6;
  const int wm   = wv & 3;
  const int wn   = wv >> 2;

  __shared__ unsigned short As[256][72];
  __shared__ unsigned short Bs[64][72];

  f32x4 acc[4][2] = {};

  const int kb = s << 9;  // s*512

  const unsigned short* Ap = A + (size_t)(t >> 3) * 16384 + kb + ((t & 7) << 3);
  const float* Bp = Wm + (size_t)(n0 + (t >> 4)) * 16384 + kb + ((t & 15) << 2);

  us8 qa[4]; f32x4 qb[2];

#define K3_LOAD(k0) do {                                                      \
    _Pragma("unroll")                                                         \
    for (int p = 0; p < 4; ++p)                                               \
      qa[p] = *(const us8*)(Ap + (size_t)(p << 6) * 16384 + (k0));            \
    _Pragma("unroll")                                                         \
    for (int p = 0; p < 2; ++p)                                               \
      qb[p] = *(const f32x4*)(Bp + (size_t)(p << 5) * 16384 + (k0));          \
  } while (0)

#define K3_WRITE() do {                                                       \
    _Pragma("unroll")                                                         \
    for (int p = 0; p < 4; ++p)                                               \
      *(us8*)&As[(p << 6) + (t >> 3)][(t & 7) << 3] = qa[p];                  \
    _Pragma("unroll")                                                         \
    for (int p = 0; p < 2; ++p)                                               \
      *(us4*)&Bs[(p << 5) + (t >> 4)][(t & 15) << 2] = cvt4(qb[p]);           \
  } while (0)

#define K3_COMPUTE() do {                                                     \
    const int fr = lane & 15;                                                 \
    const int kc = (lane >> 4) << 3;                                          \
    _Pragma("unroll")                                                         \
    for (int kk = 0; kk < 2; ++kk) {                                          \
      short8 a[4], b[2];                                                      \
      _Pragma("unroll")                                                       \
      for (int i = 0; i < 4; ++i)                                             \
        a[i] = *(const short8*)&As[(wm << 6) + (i << 4) + fr][(kk << 5) + kc];\
      _Pragma("unroll")                                                       \
      for (int j = 0; j < 2; ++j)                                             \
        b[j] = *(const short8*)&Bs[(wn << 5) + (j << 4) + fr][(kk << 5) + kc];\
      _Pragma("unroll")                                                       \
      for (int i = 0; i < 4; ++i)                                             \
        _Pragma("unroll")                                                     \
        for (int j = 0; j < 2; ++j)                                           \
          acc[i][j] = __builtin_amdgcn_mfma_f32_16x16x32_bf16(a[i], b[j], acc[i][j], 0, 0, 0); \
    }                                                                         \
  } while (0)

  K3_LOAD(0);
  K3_WRITE();
  sync_ds();
  for (int k0 = 64; k0 < 512; k0 += 64) {
    K3_LOAD(k0);
    K3_COMPUTE();
    sync_ds();
    K3_WRITE();
    sync_ds();
  }
  K3_COMPUTE();

  const int col16 = lane & 15;
  const int row4  = (lane >> 4) << 2;
  float* outp = part + (size_t)s * BATCH * 1024;
#pragma unroll
  for (int i = 0; i < 4; ++i)
#pragma unroll
    for (int j = 0; j < 2; ++j)
#pragma unroll
      for (int r = 0; r < 4; ++r)
        outp[(size_t)((wm << 6) + (i << 4) + row4 + r) * 1024
             + n0 + (wn << 5) + (j << 4) + col16] = acc[i][j][r];
#undef K3_LOAD
#undef K3_WRITE
#undef K3_COMPUTE
}

// ---------------------------------------------------------------------------
// K4: fused head. Per batch row: reduce SPLIT partials + bias + relu,
//     dot with w2, block-reduce -> out[b].
// ---------------------------------------------------------------------------
__global__ __launch_bounds__(256) void k4_head(
    const float* __restrict__ part,   // [SPLIT][BATCH][1024]
    const float* __restrict__ b1,     // [1024]
    const float* __restrict__ w2,     // [1024]
    const float* __restrict__ b2,     // [1]
    float* __restrict__ out)          // [BATCH]
{
  const int b = blockIdx.x;
  const int t = threadIdx.x;
  float accum = 0.0f;
#pragma unroll
  for (int nn = 0; nn < 4; ++nn) {
    const int n = nn * 256 + t;
    float s = b1[n];
#pragma unroll 8
    for (int sp = 0; sp < SPLIT; ++sp)
      s += part[((size_t)sp * BATCH + b) * 1024 + n];
    accum += fmaxf(s, 0.0f) * w2[n];
  }
  __shared__ float red[4];
#pragma unroll
  for (int off = 32; off > 0; off >>= 1)
    accum += __shfl_down(accum, off);
  if ((t & 63) == 0) red[t >> 6] = accum;
  __syncthreads();
  if (t == 0) out[b] = red[0] + red[1] + red[2] + red[3] + b2[0];
}

// ---------------------------------------------------------------------------
extern "C" void kernel_launch(void* const* d_in, const int* in_sizes, int n_in,
                              void* d_out, int out_size, void* d_ws, size_t ws_size,
                              hipStream_t stream) {
  const float* inputs = (const float*)d_in[0];
  const float* W_ih   = (const float*)d_in[1];
  // d_in[2] = W_hh: unused (h0 == 0)
  const float* b_ih   = (const float*)d_in[3];
  const float* b_hh   = (const float*)d_in[4];
  const float* imp    = (const float*)d_in[5];
  const float* m1w    = (const float*)d_in[6];
  const float* m1b    = (const float*)d_in[7];
  const float* m2w    = (const float*)d_in[8];
  const float* m2b    = (const float*)d_in[9];
  float* out = (float*)d_out;

  char* ws = (char*)d_ws;
  unsigned short* agg = (unsigned short*)ws;        // 8 MB [256][16384] bf16
  float* part         = (float*)(ws + (8u << 20));  // 32 MB [32][256][1024] f32

  k1_gates_fused<<<dim3(512), 512, 0, stream>>>(inputs, W_ih, b_ih, b_hh, imp, agg);
  k3_mlp1       <<<dim3(512), 512, 0, stream>>>(agg, m1w, part);
  k4_head       <<<dim3(256), 256, 0, stream>>>(part, m1b, m2w, m2b, out);
}

// Round 4
// 89.193 us; speedup vs baseline: 1.4937x; 1.1549x over previous
//
#include <hip/hip_runtime.h>
#include <hip/hip_bf16.h>
#include <stdint.h>

#define NVAR 32
#define LAGD 1024
#define BATCH 256
#define HDIM 512
#define SPLIT 32

typedef __attribute__((ext_vector_type(4))) float f32x4;
typedef __attribute__((ext_vector_type(8))) short short8;
typedef __attribute__((ext_vector_type(4))) unsigned short us4;
typedef __attribute__((ext_vector_type(8))) unsigned short us8;

__device__ __forceinline__ unsigned short f2bf(float f) {
  union { __hip_bfloat16 b; unsigned short s; } cv;
  cv.b = __float2bfloat16(f);
  return cv.s;
}
__device__ __forceinline__ us8 cvt8(f32x4 a, f32x4 b) {
  us8 u;
#pragma unroll
  for (int e = 0; e < 4; ++e) { u[e] = f2bf(a[e]); u[4 + e] = f2bf(b[e]); }
  return u;
}

// global -> LDS direct copy, 16 B per lane. LDS dest = wave-uniform base
// (+ lane*16 by HW); global src is per-lane. CK-style addrspace casts.
__device__ __forceinline__ void gload16(const void* g, const void* l) {
  __builtin_amdgcn_global_load_lds(
      (const __attribute__((address_space(1))) unsigned int*)(uintptr_t)g,
      (__attribute__((address_space(3))) unsigned int*)(unsigned int)(uintptr_t)l,
      16, 0, 0);
}

// Order-pinned global load (asm volatile keeps FIFO position vs gload16).
__device__ __forceinline__ f32x4 gldx4(const float* p) {
  f32x4 r;
  asm volatile("global_load_dwordx4 %0, %1, off" : "=v"(r) : "v"(p) : "memory");
  return r;
}

// Counted vmem wait; sched_barrier stops hipcc hoisting dependent VALU above it.
#define WAITVM(N) do { \
    asm volatile("s_waitcnt vmcnt(" #N ")" ::: "memory"); \
    __builtin_amdgcn_sched_barrier(0); } while (0)

// Barrier that does NOT drain vmcnt (prefetch survives across it).
__device__ __forceinline__ void sync_ds() {
  asm volatile("s_waitcnt lgkmcnt(0)" ::: "memory");
  __builtin_amdgcn_s_barrier();
}

// ---------------------------------------------------------------------------
// K0: X fp32 -> bf16, tiled [32 v][16 kt][256 m][64 k] with XOR swizzle
//     byte = (m*128 + k*2) ^ ((m&7)<<4)  within each 32 KB tile.
// ---------------------------------------------------------------------------
__global__ __launch_bounds__(256) void k0_tileX(
    const float* __restrict__ X,          // [256][32][1024]
    unsigned short* __restrict__ Xbf)     // tiled
{
  const int v = blockIdx.x >> 4, kt = blockIdx.x & 15;
  const int t = threadIdx.x;
  const int rt = t >> 3, c8 = (t & 7) << 3;
  const float* src = X + (size_t)rt * (NVAR * LAGD) + (size_t)v * LAGD + kt * 64 + c8;
  char* dst = (char*)Xbf + ((size_t)v * 16 + kt) * 32768;
#pragma unroll
  for (int p = 0; p < 8; ++p) {
    const int r = (p << 5) + rt;
    f32x4 a = *(const f32x4*)(src + (size_t)(p << 5) * (NVAR * LAGD));
    f32x4 b = *(const f32x4*)(src + (size_t)(p << 5) * (NVAR * LAGD) + 4);
    *(us8*)(dst + (((r << 7) + (c8 << 1)) ^ ((r & 7) << 4))) = cvt8(a, b);
  }
}

// ---------------------------------------------------------------------------
// K1: gates GEMM + LSTM activation, counted-vmcnt pipeline.
//   Block (v, h-tile 32). A: Xbf tiles via gload_lds (dbuf). B: W fp32 via
//   asm reg-prefetch depth-2 + cvt. 16 K-tiles of 64.
// ---------------------------------------------------------------------------
__global__ __launch_bounds__(512, 4) void k1_gates(
    const unsigned short* __restrict__ Xbf,
    const float* __restrict__ W,          // [32][2048][1024]
    const float* __restrict__ b_ih,
    const float* __restrict__ b_hh,
    const float* __restrict__ imp,
    unsigned short* __restrict__ aggT)    // [32 v][8 kt][256][64] swizzled bf16
{
  const int bid = blockIdx.x;
  const int chunk = ((bid & 7) << 6) | (bid >> 3);   // XCD-contiguous
  const int v = chunk >> 4;
  const int h0 = (chunk & 15) << 5;

  const int t = threadIdx.x, lane = t & 63, wave = t >> 6;
  const int wm = wave & 3, wh = wave >> 2;

  __shared__ __align__(16) unsigned char smem[81920]; // A:2x32K @0, B:2x8K @65536

  const char* Asrc = (const char*)Xbf + (size_t)v * 16 * 32768 + wave * 1024 + lane * 16;
  const unsigned aoff = wave * 1024u;

  const int brow = t >> 3;
  const int wrow = (brow < 32) ? (h0 + brow) : (1024 + h0 + brow - 32);
  const float* Bsrc = W + (size_t)v * (2048 * LAGD) + (size_t)wrow * LAGD + ((t & 7) << 3);
  const unsigned bwoff = (unsigned)(((brow << 7) + ((t & 7) << 4)) ^ ((brow & 7) << 4));

  f32x4 acc_i[4] = {}, acc_g[4] = {};
  f32x4 pbA[2], pbB[2];

#define GLA(BUF, KT) do { \
    _Pragma("unroll") for (int _r = 0; _r < 4; ++_r) \
      gload16(Asrc + (KT) * 32768 + _r * 8192, \
              smem + (BUF) * 32768u + aoff + _r * 8192); } while (0)

#define BLOAD(PB, KT) do { \
    (PB)[0] = gldx4(Bsrc + (KT) * 64); \
    (PB)[1] = gldx4(Bsrc + (KT) * 64 + 4); } while (0)

#define BSTORE(BUF, PB) \
    *(us8*)(smem + 65536u + (BUF) * 8192u + bwoff) = cvt8((PB)[0], (PB)[1])

#define COMP(BUF) do { \
    const unsigned char* Ab = smem + (BUF) * 32768u; \
    const unsigned char* Bb = smem + 65536u + (BUF) * 8192u; \
    const int fr = lane & 15, k16 = (lane >> 4) << 4; \
    _Pragma("unroll") for (int kk = 0; kk < 2; ++kk) { \
      short8 a[4], fi, fg; \
      _Pragma("unroll") for (int i = 0; i < 4; ++i) { \
        const int rw = (wm << 6) + (i << 4) + fr; \
        a[i] = *(const short8*)(Ab + (((rw << 7) + (kk << 6) + k16) ^ ((rw & 7) << 4))); \
      } \
      { const int rw = (wh << 4) + fr; \
        fi = *(const short8*)(Bb + (((rw << 7) + (kk << 6) + k16) ^ ((rw & 7) << 4))); \
        fg = *(const short8*)(Bb + ((((rw + 32) << 7) + (kk << 6) + k16) ^ ((rw & 7) << 4))); } \
      _Pragma("unroll") for (int i = 0; i < 4; ++i) { \
        acc_i[i] = __builtin_amdgcn_mfma_f32_16x16x32_bf16(a[i], fi, acc_i[i], 0, 0, 0); \
        acc_g[i] = __builtin_amdgcn_mfma_f32_16x16x32_bf16(a[i], fg, acc_g[i], 0, 0, 0); } \
    } } while (0)

#define STEP(CUR, NXT, PBP, PBN, KT) do { \
    GLA(NXT, (KT) + 1); \
    BLOAD(PBN, (KT) + 2); \
    COMP(CUR); \
    WAITVM(6);  /* drain PBP(oldest 2); GLA(4)+PBN(2) stay */ \
    BSTORE(NXT, PBP); \
    WAITVM(2);  /* drain GLA; PBN stays in flight */ \
    sync_ds(); } while (0)

  // prologue: tile0 into buf0, B(0) and B(1) into regs
  GLA(0, 0);
  BLOAD(pbA, 0);
  BLOAD(pbB, 1);
  WAITVM(2);          // drain GLA0 + pbA; pbB stays
  BSTORE(0, pbA);
  sync_ds();

#pragma unroll
  for (int kt = 0; kt < 14; kt += 2) {
    STEP(0, 1, pbB, pbA, kt);
    STEP(1, 0, pbA, pbB, kt + 1);
  }
  // kt = 14 tail (no more B prefetch)
  GLA(1, 15);
  COMP(0);
  WAITVM(4);          // drain pbB(tile15); GLA stays
  BSTORE(1, pbB);
  WAITVM(0);
  sync_ds();
  COMP(1);            // tile 15

  // epilogue: c = sigmoid(i+bi)*tanh(g+bg)*imp -> aggT (swizzled tile layout)
  const int col16 = lane & 15, row4 = (lane >> 4) << 2;
  const float impv = imp[v];
  const int h = h0 + (wh << 4) + col16;
  const float bsi = b_ih[v * 2048 + h] + b_hh[v * 2048 + h];
  const float bsg = b_ih[v * 2048 + 1024 + h] + b_hh[v * 2048 + 1024 + h];
  char* obase = (char*)aggT + ((size_t)v * 8 + (h >> 6)) * 32768;
  const int hc = h & 63;
#pragma unroll
  for (int i = 0; i < 4; ++i)
#pragma unroll
    for (int r = 0; r < 4; ++r) {
      const int m = (wm << 6) + (i << 4) + row4 + r;
      const float ii = acc_i[i][r] + bsi;
      const float gg = acc_g[i][r] + bsg;
      const float c = (1.0f / (1.0f + __expf(-ii))) * tanhf(gg) * impv;
      *(unsigned short*)(obase + (((m << 7) + (hc << 1)) ^ ((m & 7) << 4))) = f2bf(c);
    }
#undef STEP
#undef COMP
#undef GLA
#undef BLOAD
#undef BSTORE
}

// ---------------------------------------------------------------------------
// K3: mlp1 split-K GEMM, same pipeline. Block (split s = var, n-tile 64).
//   A: aggT tiles via gload_lds. B: m1w fp32 rows n0..n0+63, k-slice s*512.
//   8 K-tiles of 64.
// ---------------------------------------------------------------------------
__global__ __launch_bounds__(512, 4) void k3_mlp1(
    const unsigned short* __restrict__ aggT,
    const float* __restrict__ Wm,          // [1024][16384]
    float* __restrict__ part)              // [32][256][1024]
{
  const int bid = blockIdx.x;
  const int chunk = ((bid & 7) << 6) | (bid >> 3);
  const int s = chunk >> 4;
  const int n0 = (chunk & 15) << 6;

  const int t = threadIdx.x, lane = t & 63, wave = t >> 6;
  const int wm = wave & 3, wn = wave >> 2;

  __shared__ __align__(16) unsigned char smem[81920];

  const char* Asrc = (const char*)aggT + (size_t)s * 8 * 32768 + wave * 1024 + lane * 16;
  const unsigned aoff = wave * 1024u;

  const int brow = t >> 3;
  const float* Bsrc = Wm + (size_t)(n0 + brow) * 16384 + (size_t)s * 512 + ((t & 7) << 3);
  const unsigned bwoff = (unsigned)(((brow << 7) + ((t & 7) << 4)) ^ ((brow & 7) << 4));

  f32x4 acc[4][2] = {};
  f32x4 pbA[2], pbB[2];

#define GLA(BUF, KT) do { \
    _Pragma("unroll") for (int _r = 0; _r < 4; ++_r) \
      gload16(Asrc + (KT) * 32768 + _r * 8192, \
              smem + (BUF) * 32768u + aoff + _r * 8192); } while (0)

#define BLOAD(PB, KT) do { \
    (PB)[0] = gldx4(Bsrc + (KT) * 64); \
    (PB)[1] = gldx4(Bsrc + (KT) * 64 + 4); } while (0)

#define BSTORE(BUF, PB) \
    *(us8*)(smem + 65536u + (BUF) * 8192u + bwoff) = cvt8((PB)[0], (PB)[1])

#define COMP(BUF) do { \
    const unsigned char* Ab = smem + (BUF) * 32768u; \
    const unsigned char* Bb = smem + 65536u + (BUF) * 8192u; \
    const int fr = lane & 15, k16 = (lane >> 4) << 4; \
    _Pragma("unroll") for (int kk = 0; kk < 2; ++kk) { \
      short8 a[4], b[2]; \
      _Pragma("unroll") for (int i = 0; i < 4; ++i) { \
        const int rw = (wm << 6) + (i << 4) + fr; \
        a[i] = *(const short8*)(Ab + (((rw << 7) + (kk << 6) + k16) ^ ((rw & 7) << 4))); \
      } \
      _Pragma("unroll") for (int j = 0; j < 2; ++j) { \
        const int rw = (wn << 5) + (j << 4) + fr; \
        b[j] = *(const short8*)(Bb + (((rw << 7) + (kk << 6) + k16) ^ ((rw & 7) << 4))); \
      } \
      _Pragma("unroll") for (int i = 0; i < 4; ++i) \
        _Pragma("unroll") for (int j = 0; j < 2; ++j) \
          acc[i][j] = __builtin_amdgcn_mfma_f32_16x16x32_bf16(a[i], b[j], acc[i][j], 0, 0, 0); \
    } } while (0)

#define STEP(CUR, NXT, PBP, PBN, KT) do { \
    GLA(NXT, (KT) + 1); \
    BLOAD(PBN, (KT) + 2); \
    COMP(CUR); \
    WAITVM(6); \
    BSTORE(NXT, PBP); \
    WAITVM(2); \
    sync_ds(); } while (0)

  GLA(0, 0);
  BLOAD(pbA, 0);
  BLOAD(pbB, 1);
  WAITVM(2);
  BSTORE(0, pbA);
  sync_ds();

#pragma unroll
  for (int kt = 0; kt < 6; kt += 2) {
    STEP(0, 1, pbB, pbA, kt);
    STEP(1, 0, pbA, pbB, kt + 1);
  }
  // kt = 6 tail
  GLA(1, 7);
  COMP(0);
  WAITVM(4);
  BSTORE(1, pbB);
  WAITVM(0);
  sync_ds();
  COMP(1);            // tile 7

  const int col16 = lane & 15, row4 = (lane >> 4) << 2;
  float* outp = part + (size_t)s * BATCH * 1024;
#pragma unroll
  for (int i = 0; i < 4; ++i)
#pragma unroll
    for (int j = 0; j < 2; ++j)
#pragma unroll
      for (int r = 0; r < 4; ++r)
        outp[(size_t)((wm << 6) + (i << 4) + row4 + r) * 1024
             + n0 + (wn << 5) + (j << 4) + col16] = acc[i][j][r];
#undef STEP
#undef COMP
#undef GLA
#undef BLOAD
#undef BSTORE
}

// ---------------------------------------------------------------------------
// K4: fused head. Per batch row: reduce SPLIT partials + bias + relu,
//     dot with w2 -> out[b].
// ---------------------------------------------------------------------------
__global__ __launch_bounds__(256) void k4_head(
    const float* __restrict__ part,   // [32][256][1024]
    const float* __restrict__ b1,
    const float* __restrict__ w2,
    const float* __restrict__ b2,
    float* __restrict__ out)
{
  const int b = blockIdx.x;
  const int t = threadIdx.x;
  float accum = 0.0f;
#pragma unroll
  for (int nn = 0; nn < 4; ++nn) {
    const int n = nn * 256 + t;
    float s = b1[n];
#pragma unroll 8
    for (int sp = 0; sp < SPLIT; ++sp)
      s += part[((size_t)sp * BATCH + b) * 1024 + n];
    accum += fmaxf(s, 0.0f) * w2[n];
  }
  __shared__ float red[4];
#pragma unroll
  for (int off = 32; off > 0; off >>= 1)
    accum += __shfl_down(accum, off);
  if ((t & 63) == 0) red[t >> 6] = accum;
  __syncthreads();
  if (t == 0) out[b] = red[0] + red[1] + red[2] + red[3] + b2[0];
}

// ---------------------------------------------------------------------------
extern "C" void kernel_launch(void* const* d_in, const int* in_sizes, int n_in,
                              void* d_out, int out_size, void* d_ws, size_t ws_size,
                              hipStream_t stream) {
  const float* inputs = (const float*)d_in[0];
  const float* W_ih   = (const float*)d_in[1];
  // d_in[2] = W_hh: unused (h0 == 0)
  const float* b_ih   = (const float*)d_in[3];
  const float* b_hh   = (const float*)d_in[4];
  const float* imp    = (const float*)d_in[5];
  const float* m1w    = (const float*)d_in[6];
  const float* m1b    = (const float*)d_in[7];
  const float* m2w    = (const float*)d_in[8];
  const float* m2b    = (const float*)d_in[9];
  float* out = (float*)d_out;

  char* ws = (char*)d_ws;
  unsigned short* Xbf  = (unsigned short*)ws;               // 16 MB tiled bf16
  unsigned short* aggT = (unsigned short*)(ws + (16u << 20)); // 8 MB tiled bf16
  float* part          = (float*)(ws + (24u << 20));        // 32 MB

  k0_tileX<<<dim3(512), 256, 0, stream>>>(inputs, Xbf);
  k1_gates<<<dim3(512), 512, 0, stream>>>(Xbf, W_ih, b_ih, b_hh, imp, aggT);
  k3_mlp1 <<<dim3(512), 512, 0, stream>>>(aggT, m1w, part);
  k4_head <<<dim3(256), 256, 0, stream>>>(part, m1b, m2w, m2b, out);
}

// Round 5
// 73.953 us; speedup vs baseline: 1.8015x; 1.2061x over previous
//
#include <hip/hip_runtime.h>
#include <hip/hip_bf16.h>
#include <stdint.h>

#define NVAR 32
#define LAGD 1024
#define BATCH 256
#define HDIM 512
#define SPLIT 32

typedef __attribute__((ext_vector_type(4))) float f32x4;
typedef __attribute__((ext_vector_type(8))) short short8;
typedef __attribute__((ext_vector_type(4))) unsigned short us4;
typedef __attribute__((ext_vector_type(8))) unsigned short us8;

__device__ __forceinline__ unsigned short f2bf(float f) {
  union { __hip_bfloat16 b; unsigned short s; } cv;
  cv.b = __float2bfloat16(f);
  return cv.s;
}
__device__ __forceinline__ us8 cvt8(f32x4 a, f32x4 b) {
  us8 u;
#pragma unroll
  for (int e = 0; e < 4; ++e) { u[e] = f2bf(a[e]); u[4 + e] = f2bf(b[e]); }
  return u;
}

// global -> LDS direct copy, 16 B per lane. LDS dest = wave-uniform base
// (+ lane*16 by HW); global src is per-lane.
__device__ __forceinline__ void gload16(const void* g, const void* l) {
  __builtin_amdgcn_global_load_lds(
      (const __attribute__((address_space(1))) unsigned int*)(uintptr_t)g,
      (__attribute__((address_space(3))) unsigned int*)(unsigned int)(uintptr_t)l,
      16, 0, 0);
}

// Order-pinned global load (asm volatile keeps FIFO position vs gload16).
__device__ __forceinline__ f32x4 gldx4(const float* p) {
  f32x4 r;
  asm volatile("global_load_dwordx4 %0, %1, off" : "=v"(r) : "v"(p) : "memory");
  return r;
}

// Counted vmem wait; sched_barrier stops hipcc hoisting dependent VALU above it.
#define WAITVM(N) do { \
    asm volatile("s_waitcnt vmcnt(" #N ")" ::: "memory"); \
    __builtin_amdgcn_sched_barrier(0); } while (0)

// Barrier that does NOT drain vmcnt (prefetch survives across it).
__device__ __forceinline__ void sync_ds() {
  asm volatile("s_waitcnt lgkmcnt(0)" ::: "memory");
  __builtin_amdgcn_s_barrier();
}

// ---------------------------------------------------------------------------
// K0: X fp32 -> bf16, tiled [32 v][16 kt][256 m][64 k] with XOR swizzle
//     byte = (m*128 + k*2) ^ ((m&7)<<4)  within each 32 KB tile.
//     Grid 1024: block = (v, kt, m-half) -> 4 blocks/CU for latency hiding.
// ---------------------------------------------------------------------------
__global__ __launch_bounds__(256) void k0_tileX(
    const float* __restrict__ X,          // [256][32][1024]
    unsigned short* __restrict__ Xbf)     // tiled
{
  const int v = blockIdx.x >> 5, kt = (blockIdx.x >> 1) & 15, mh = blockIdx.x & 1;
  const int t = threadIdx.x;
  const int rt = (mh << 7) + (t >> 3), c8 = (t & 7) << 3;
  const float* src = X + (size_t)rt * (NVAR * LAGD) + (size_t)v * LAGD + kt * 64 + c8;
  char* dst = (char*)Xbf + ((size_t)v * 16 + kt) * 32768;
#pragma unroll
  for (int p = 0; p < 4; ++p) {
    const int r = (p << 5) + rt;
    f32x4 a = *(const f32x4*)(src + (size_t)(p << 5) * (NVAR * LAGD));
    f32x4 b = *(const f32x4*)(src + (size_t)(p << 5) * (NVAR * LAGD) + 4);
    *(us8*)(dst + (((r << 7) + (c8 << 1)) ^ ((r & 7) << 4))) = cvt8(a, b);
  }
}

// ---------------------------------------------------------------------------
// K1: gates GEMM + LSTM activation, counted-vmcnt pipeline.
//   Block (v, h-tile 32). A: Xbf tiles via gload_lds (dbuf). B: W fp32 via
//   asm reg-prefetch depth-2 + cvt. 16 K-tiles of 64.
// ---------------------------------------------------------------------------
__global__ __launch_bounds__(512, 4) void k1_gates(
    const unsigned short* __restrict__ Xbf,
    const float* __restrict__ W,          // [32][2048][1024]
    const float* __restrict__ b_ih,
    const float* __restrict__ b_hh,
    const float* __restrict__ imp,
    unsigned short* __restrict__ aggT)    // [32 v][8 kt][256][64] swizzled bf16
{
  const int bid = blockIdx.x;
  const int chunk = ((bid & 7) << 6) | (bid >> 3);   // XCD-contiguous
  const int v = chunk >> 4;
  const int h0 = (chunk & 15) << 5;

  const int t = threadIdx.x, lane = t & 63, wave = t >> 6;
  const int wm = wave & 3, wh = wave >> 2;

  __shared__ __align__(16) unsigned char smem[81920]; // A:2x32K @0, B:2x8K @65536

  const char* Asrc = (const char*)Xbf + (size_t)v * 16 * 32768 + wave * 1024 + lane * 16;
  const unsigned aoff = wave * 1024u;

  const int brow = t >> 3;
  const int wrow = (brow < 32) ? (h0 + brow) : (1024 + h0 + brow - 32);
  const float* Bsrc = W + (size_t)v * (2048 * LAGD) + (size_t)wrow * LAGD + ((t & 7) << 3);
  const unsigned bwoff = (unsigned)(((brow << 7) + ((t & 7) << 4)) ^ ((brow & 7) << 4));

  f32x4 acc_i[4] = {}, acc_g[4] = {};
  f32x4 pbA[2], pbB[2];

#define GLA(BUF, KT) do { \
    _Pragma("unroll") for (int _r = 0; _r < 4; ++_r) \
      gload16(Asrc + (KT) * 32768 + _r * 8192, \
              smem + (BUF) * 32768u + aoff + _r * 8192); } while (0)

#define BLOAD(PB, KT) do { \
    (PB)[0] = gldx4(Bsrc + (KT) * 64); \
    (PB)[1] = gldx4(Bsrc + (KT) * 64 + 4); } while (0)

#define BSTORE(BUF, PB) \
    *(us8*)(smem + 65536u + (BUF) * 8192u + bwoff) = cvt8((PB)[0], (PB)[1])

#define COMP(BUF) do { \
    const unsigned char* Ab = smem + (BUF) * 32768u; \
    const unsigned char* Bb = smem + 65536u + (BUF) * 8192u; \
    const int fr = lane & 15, k16 = (lane >> 4) << 4; \
    _Pragma("unroll") for (int kk = 0; kk < 2; ++kk) { \
      short8 a[4], fi, fg; \
      _Pragma("unroll") for (int i = 0; i < 4; ++i) { \
        const int rw = (wm << 6) + (i << 4) + fr; \
        a[i] = *(const short8*)(Ab + (((rw << 7) + (kk << 6) + k16) ^ ((rw & 7) << 4))); \
      } \
      { const int rw = (wh << 4) + fr; \
        fi = *(const short8*)(Bb + (((rw << 7) + (kk << 6) + k16) ^ ((rw & 7) << 4))); \
        fg = *(const short8*)(Bb + ((((rw + 32) << 7) + (kk << 6) + k16) ^ ((rw & 7) << 4))); } \
      _Pragma("unroll") for (int i = 0; i < 4; ++i) { \
        acc_i[i] = __builtin_amdgcn_mfma_f32_16x16x32_bf16(a[i], fi, acc_i[i], 0, 0, 0); \
        acc_g[i] = __builtin_amdgcn_mfma_f32_16x16x32_bf16(a[i], fg, acc_g[i], 0, 0, 0); } \
    } } while (0)

#define STEP(CUR, NXT, PBP, PBN, KT) do { \
    GLA(NXT, (KT) + 1); \
    BLOAD(PBN, (KT) + 2); \
    COMP(CUR); \
    WAITVM(6);  /* drain PBP(oldest 2); GLA(4)+PBN(2) stay */ \
    BSTORE(NXT, PBP); \
    WAITVM(2);  /* drain GLA; PBN stays in flight */ \
    sync_ds(); } while (0)

  // prologue: tile0 into buf0, B(0) and B(1) into regs
  GLA(0, 0);
  BLOAD(pbA, 0);
  BLOAD(pbB, 1);
  WAITVM(2);          // drain GLA0 + pbA; pbB stays
  BSTORE(0, pbA);
  sync_ds();

#pragma unroll
  for (int kt = 0; kt < 14; kt += 2) {
    STEP(0, 1, pbB, pbA, kt);
    STEP(1, 0, pbA, pbB, kt + 1);
  }
  // kt = 14 tail (no more B prefetch)
  GLA(1, 15);
  COMP(0);
  WAITVM(4);          // drain pbB(tile15); GLA stays
  BSTORE(1, pbB);
  WAITVM(0);
  sync_ds();
  COMP(1);            // tile 15

  // epilogue: c = sigmoid(i+bi)*tanh(g+bg)*imp -> aggT (swizzled tile layout)
  const int col16 = lane & 15, row4 = (lane >> 4) << 2;
  const float impv = imp[v];
  const int h = h0 + (wh << 4) + col16;
  const float bsi = b_ih[v * 2048 + h] + b_hh[v * 2048 + h];
  const float bsg = b_ih[v * 2048 + 1024 + h] + b_hh[v * 2048 + 1024 + h];
  char* obase = (char*)aggT + ((size_t)v * 8 + (h >> 6)) * 32768;
  const int hc = h & 63;
#pragma unroll
  for (int i = 0; i < 4; ++i)
#pragma unroll
    for (int r = 0; r < 4; ++r) {
      const int m = (wm << 6) + (i << 4) + row4 + r;
      const float ii = acc_i[i][r] + bsi;
      const float gg = acc_g[i][r] + bsg;
      const float c = (1.0f / (1.0f + __expf(-ii))) * tanhf(gg) * impv;
      *(unsigned short*)(obase + (((m << 7) + (hc << 1)) ^ ((m & 7) << 4))) = f2bf(c);
    }
#undef STEP
#undef COMP
#undef GLA
#undef BLOAD
#undef BSTORE
}

// ---------------------------------------------------------------------------
// K3: mlp1 split-K GEMM, same pipeline. Block (split s = var, n-tile 64).
//   A: aggT tiles via gload_lds. B: m1w fp32 rows n0..n0+63, k-slice s*512.
//   8 K-tiles of 64.  Output partials in bf16 (values ~1e-3, safe).
// ---------------------------------------------------------------------------
__global__ __launch_bounds__(512, 4) void k3_mlp1(
    const unsigned short* __restrict__ aggT,
    const float* __restrict__ Wm,          // [1024][16384]
    unsigned short* __restrict__ part)     // [32][256][1024] bf16
{
  const int bid = blockIdx.x;
  const int chunk = ((bid & 7) << 6) | (bid >> 3);
  const int s = chunk >> 4;
  const int n0 = (chunk & 15) << 6;

  const int t = threadIdx.x, lane = t & 63, wave = t >> 6;
  const int wm = wave & 3, wn = wave >> 2;

  __shared__ __align__(16) unsigned char smem[81920];

  const char* Asrc = (const char*)aggT + (size_t)s * 8 * 32768 + wave * 1024 + lane * 16;
  const unsigned aoff = wave * 1024u;

  const int brow = t >> 3;
  const float* Bsrc = Wm + (size_t)(n0 + brow) * 16384 + (size_t)s * 512 + ((t & 7) << 3);
  const unsigned bwoff = (unsigned)(((brow << 7) + ((t & 7) << 4)) ^ ((brow & 7) << 4));

  f32x4 acc[4][2] = {};
  f32x4 pbA[2], pbB[2];

#define GLA(BUF, KT) do { \
    _Pragma("unroll") for (int _r = 0; _r < 4; ++_r) \
      gload16(Asrc + (KT) * 32768 + _r * 8192, \
              smem + (BUF) * 32768u + aoff + _r * 8192); } while (0)

#define BLOAD(PB, KT) do { \
    (PB)[0] = gldx4(Bsrc + (KT) * 64); \
    (PB)[1] = gldx4(Bsrc + (KT) * 64 + 4); } while (0)

#define BSTORE(BUF, PB) \
    *(us8*)(smem + 65536u + (BUF) * 8192u + bwoff) = cvt8((PB)[0], (PB)[1])

#define COMP(BUF) do { \
    const unsigned char* Ab = smem + (BUF) * 32768u; \
    const unsigned char* Bb = smem + 65536u + (BUF) * 8192u; \
    const int fr = lane & 15, k16 = (lane >> 4) << 4; \
    _Pragma("unroll") for (int kk = 0; kk < 2; ++kk) { \
      short8 a[4], b[2]; \
      _Pragma("unroll") for (int i = 0; i < 4; ++i) { \
        const int rw = (wm << 6) + (i << 4) + fr; \
        a[i] = *(const short8*)(Ab + (((rw << 7) + (kk << 6) + k16) ^ ((rw & 7) << 4))); \
      } \
      _Pragma("unroll") for (int j = 0; j < 2; ++j) { \
        const int rw = (wn << 5) + (j << 4) + fr; \
        b[j] = *(const short8*)(Bb + (((rw << 7) + (kk << 6) + k16) ^ ((rw & 7) << 4))); \
      } \
      _Pragma("unroll") for (int i = 0; i < 4; ++i) \
        _Pragma("unroll") for (int j = 0; j < 2; ++j) \
          acc[i][j] = __builtin_amdgcn_mfma_f32_16x16x32_bf16(a[i], b[j], acc[i][j], 0, 0, 0); \
    } } while (0)

#define STEP(CUR, NXT, PBP, PBN, KT) do { \
    GLA(NXT, (KT) + 1); \
    BLOAD(PBN, (KT) + 2); \
    COMP(CUR); \
    WAITVM(6); \
    BSTORE(NXT, PBP); \
    WAITVM(2); \
    sync_ds(); } while (0)

  GLA(0, 0);
  BLOAD(pbA, 0);
  BLOAD(pbB, 1);
  WAITVM(2);
  BSTORE(0, pbA);
  sync_ds();

#pragma unroll
  for (int kt = 0; kt < 6; kt += 2) {
    STEP(0, 1, pbB, pbA, kt);
    STEP(1, 0, pbA, pbB, kt + 1);
  }
  // kt = 6 tail
  GLA(1, 7);
  COMP(0);
  WAITVM(4);
  BSTORE(1, pbB);
  WAITVM(0);
  sync_ds();
  COMP(1);            // tile 7

  const int col16 = lane & 15, row4 = (lane >> 4) << 2;
  unsigned short* outp = part + (size_t)s * BATCH * 1024;
#pragma unroll
  for (int i = 0; i < 4; ++i)
#pragma unroll
    for (int j = 0; j < 2; ++j)
#pragma unroll
      for (int r = 0; r < 4; ++r)
        outp[(size_t)((wm << 6) + (i << 4) + row4 + r) * 1024
             + n0 + (wn << 5) + (j << 4) + col16] = f2bf(acc[i][j][r]);
#undef STEP
#undef COMP
#undef GLA
#undef BLOAD
#undef BSTORE
}

// ---------------------------------------------------------------------------
// K4: fused head (bf16 partials). One block per batch row, 512 threads,
//     each thread owns 2 n's via one dword read per split.
// ---------------------------------------------------------------------------
__global__ __launch_bounds__(512) void k4_head(
    const unsigned short* __restrict__ part,   // [32][256][1024] bf16
    const float* __restrict__ b1,
    const float* __restrict__ w2,
    const float* __restrict__ b2,
    float* __restrict__ out)
{
  const int b = blockIdx.x;
  const int t = threadIdx.x;          // 0..511
  const int n0 = t << 1;
  float s0 = b1[n0], s1 = b1[n0 + 1];
#pragma unroll 8
  for (int sp = 0; sp < SPLIT; ++sp) {
    const unsigned u = *(const unsigned*)(part + ((size_t)sp * BATCH + b) * 1024 + n0);
    union { unsigned u; float f; } lo, hi;
    lo.u = u << 16;
    hi.u = u & 0xffff0000u;
    s0 += lo.f;
    s1 += hi.f;
  }
  float accum = fmaxf(s0, 0.0f) * w2[n0] + fmaxf(s1, 0.0f) * w2[n0 + 1];
  __shared__ float red[8];
#pragma unroll
  for (int off = 32; off > 0; off >>= 1)
    accum += __shfl_down(accum, off);
  if ((t & 63) == 0) red[t >> 6] = accum;
  __syncthreads();
  if (t == 0) {
    float r = b2[0];
#pragma unroll
    for (int w = 0; w < 8; ++w) r += red[w];
    out[b] = r;
  }
}

// ---------------------------------------------------------------------------
extern "C" void kernel_launch(void* const* d_in, const int* in_sizes, int n_in,
                              void* d_out, int out_size, void* d_ws, size_t ws_size,
                              hipStream_t stream) {
  const float* inputs = (const float*)d_in[0];
  const float* W_ih   = (const float*)d_in[1];
  // d_in[2] = W_hh: unused (h0 == 0)
  const float* b_ih   = (const float*)d_in[3];
  const float* b_hh   = (const float*)d_in[4];
  const float* imp    = (const float*)d_in[5];
  const float* m1w    = (const float*)d_in[6];
  const float* m1b    = (const float*)d_in[7];
  const float* m2w    = (const float*)d_in[8];
  const float* m2b    = (const float*)d_in[9];
  float* out = (float*)d_out;

  char* ws = (char*)d_ws;
  unsigned short* Xbf  = (unsigned short*)ws;                 // 16 MB tiled bf16
  unsigned short* aggT = (unsigned short*)(ws + (16u << 20)); // 8 MB tiled bf16
  unsigned short* part = (unsigned short*)(ws + (24u << 20)); // 16 MB bf16

  k0_tileX<<<dim3(1024), 256, 0, stream>>>(inputs, Xbf);
  k1_gates<<<dim3(512), 512, 0, stream>>>(Xbf, W_ih, b_ih, b_hh, imp, aggT);
  k3_mlp1 <<<dim3(512), 512, 0, stream>>>(aggT, m1w, part);
  k4_head <<<dim3(256), 512, 0, stream>>>(part, m1b, m2w, m2b, out);
}

// Round 6
// 69.089 us; speedup vs baseline: 1.9284x; 1.0704x over previous
//
#include <hip/hip_runtime.h>
#include <hip/hip_bf16.h>
#include <stdint.h>

#define NVAR 32
#define LAGD 1024
#define BATCH 256
#define HDIM 512
#define SPLIT 16

typedef __attribute__((ext_vector_type(4))) float f32x4;
typedef __attribute__((ext_vector_type(8))) short short8;
typedef __attribute__((ext_vector_type(4))) unsigned short us4;
typedef __attribute__((ext_vector_type(8))) unsigned short us8;

__device__ __forceinline__ unsigned short f2bf(float f) {
  union { __hip_bfloat16 b; unsigned short s; } cv;
  cv.b = __float2bfloat16(f);
  return cv.s;
}
__device__ __forceinline__ us8 cvt8(f32x4 a, f32x4 b) {
  us8 u;
#pragma unroll
  for (int e = 0; e < 4; ++e) { u[e] = f2bf(a[e]); u[4 + e] = f2bf(b[e]); }
  return u;
}
__device__ __forceinline__ us4 cvt4(f32x4 a) {
  us4 u;
#pragma unroll
  for (int e = 0; e < 4; ++e) u[e] = f2bf(a[e]);
  return u;
}

// global -> LDS direct copy, 16 B per lane (dest = wave-uniform base + lane*16).
__device__ __forceinline__ void gload16(const void* g, const void* l) {
  __builtin_amdgcn_global_load_lds(
      (const __attribute__((address_space(1))) unsigned int*)(uintptr_t)g,
      (__attribute__((address_space(3))) unsigned int*)(unsigned int)(uintptr_t)l,
      16, 0, 0);
}

// Order-pinned global load (asm volatile keeps FIFO position).
__device__ __forceinline__ f32x4 gldx4(const float* p) {
  f32x4 r;
  asm volatile("global_load_dwordx4 %0, %1, off" : "=v"(r) : "v"(p) : "memory");
  return r;
}

// Counted vmem wait; sched_barrier stops hipcc hoisting dependent ops above it.
#define WAITVM(N) do { \
    asm volatile("s_waitcnt vmcnt(" #N ")" ::: "memory"); \
    __builtin_amdgcn_sched_barrier(0); } while (0)

// Barrier that does NOT drain vmcnt (prefetch survives across it).
__device__ __forceinline__ void sync_ds() {
  asm volatile("s_waitcnt lgkmcnt(0)" ::: "memory");
  __builtin_amdgcn_s_barrier();
}

// ---------------------------------------------------------------------------
// K1: gates GEMM + LSTM activation, fp32 X staged in-kernel (K0 eliminated).
//   Block (v, h-tile 32), grid 512, 8 waves. All 16 h-blocks of a var are
//   co-resident on one XCD (chunk swizzle) -> X tiles hit L2 after 1st read.
//   A: X fp32 -> reg (depth-1) -> cvt -> swizzled LDS.  B: W fp32 reg depth-2.
//   16 K-tiles of 64, counted-vmcnt FIFO (never drains mid-loop).
// ---------------------------------------------------------------------------
__global__ __launch_bounds__(512, 4) void k1_gates(
    const float* __restrict__ X,          // [256][32][1024]
    const float* __restrict__ W,          // [32][2048][1024]
    const float* __restrict__ b_ih,
    const float* __restrict__ b_hh,
    const float* __restrict__ imp,
    unsigned short* __restrict__ aggT)    // [32 v][8 kt][256][64] swizzled bf16
{
  const int bid = blockIdx.x;
  const int chunk = ((bid & 7) << 6) | (bid >> 3);   // XCD-contiguous
  const int v = chunk >> 4;
  const int h0 = (chunk & 15) << 5;

  const int t = threadIdx.x, lane = t & 63, wave = t >> 6;
  const int wm = wave & 3, wh = wave >> 2;

  __shared__ __align__(16) unsigned char smem[81920]; // A:2x32K @0, B:2x8K @65536

  // A staging: thread owns rows rt+64p (p=0..3), 8 fp32 cols at c8
  const int rt = t >> 3, c8 = (t & 7) << 3;
  const float* Asrc = X + (size_t)rt * (NVAR * LAGD) + (size_t)v * LAGD + c8;
  const unsigned awoff = (unsigned)(((rt << 7) + (c8 << 1)) ^ ((rt & 7) << 4));

  // B staging: 64 rows (32 i + 32 g), 8 fp32 cols per thread
  const int brow = t >> 3;
  const int wrow = (brow < 32) ? (h0 + brow) : (1024 + h0 + brow - 32);
  const float* Bsrc = W + (size_t)v * (2048 * LAGD) + (size_t)wrow * LAGD + ((t & 7) << 3);
  const unsigned bwoff = (unsigned)(((brow << 7) + ((t & 7) << 4)) ^ ((brow & 7) << 4));

  f32x4 acc_i[4] = {}, acc_g[4] = {};
  f32x4 pa[4][2], pbA[2], pbB[2];

#define ALOAD(KT) do { \
    _Pragma("unroll") for (int _p = 0; _p < 4; ++_p) { \
      pa[_p][0] = gldx4(Asrc + (size_t)_p * 64 * (NVAR * LAGD) + (KT) * 64); \
      pa[_p][1] = gldx4(Asrc + (size_t)_p * 64 * (NVAR * LAGD) + (KT) * 64 + 4); \
    } } while (0)

#define ASTORE(BUF) do { \
    _Pragma("unroll") for (int _p = 0; _p < 4; ++_p) \
      *(us8*)(smem + (BUF) * 32768u + awoff + _p * 8192u) = cvt8(pa[_p][0], pa[_p][1]); \
  } while (0)

#define BLOAD(PB, KT) do { \
    (PB)[0] = gldx4(Bsrc + (KT) * 64); \
    (PB)[1] = gldx4(Bsrc + (KT) * 64 + 4); } while (0)

#define BSTORE(BUF, PB) \
    *(us8*)(smem + 65536u + (BUF) * 8192u + bwoff) = cvt8((PB)[0], (PB)[1])

#define COMP(BUF) do { \
    const unsigned char* Ab = smem + (BUF) * 32768u; \
    const unsigned char* Bb = smem + 65536u + (BUF) * 8192u; \
    const int fr = lane & 15, k16 = (lane >> 4) << 4; \
    _Pragma("unroll") for (int kk = 0; kk < 2; ++kk) { \
      short8 a[4], fi, fg; \
      _Pragma("unroll") for (int i = 0; i < 4; ++i) { \
        const int rw = (wm << 6) + (i << 4) + fr; \
        a[i] = *(const short8*)(Ab + (((rw << 7) + (kk << 6) + k16) ^ ((rw & 7) << 4))); \
      } \
      { const int rw = (wh << 4) + fr; \
        fi = *(const short8*)(Bb + (((rw << 7) + (kk << 6) + k16) ^ ((rw & 7) << 4))); \
        fg = *(const short8*)(Bb + ((((rw + 32) << 7) + (kk << 6) + k16) ^ ((rw & 7) << 4))); } \
      _Pragma("unroll") for (int i = 0; i < 4; ++i) { \
        acc_i[i] = __builtin_amdgcn_mfma_f32_16x16x32_bf16(a[i], fi, acc_i[i], 0, 0, 0); \
        acc_g[i] = __builtin_amdgcn_mfma_f32_16x16x32_bf16(a[i], fg, acc_g[i], 0, 0, 0); } \
    } } while (0)

  // STEP invariant at entry: in-flight = B(KT+1) (2 loads).
#define STEP(CUR, NXT, PBP, PBN, KT) do { \
    ALOAD((KT) + 1);        /* 8 loads */ \
    BLOAD(PBN, (KT) + 2);   /* 2 loads */ \
    COMP(CUR); \
    WAITVM(2);   /* drain B(KT+1) + A(KT+1); keep B(KT+2) */ \
    ASTORE(NXT); \
    BSTORE(NXT, PBP); \
    sync_ds(); } while (0)

  // prologue
  ALOAD(0);
  BLOAD(pbA, 0);
  BLOAD(pbB, 1);
  WAITVM(2);          // drain A(0)+pbA; pbB stays
  ASTORE(0);
  BSTORE(0, pbA);
  sync_ds();

#pragma unroll
  for (int kt = 0; kt < 14; kt += 2) {
    STEP(0, 1, pbB, pbA, kt);
    STEP(1, 0, pbA, pbB, kt + 1);
  }
  // tail: buf0 holds tile 14; pbB = B(15) in flight
  ALOAD(15);
  COMP(0);            // tile 14
  WAITVM(0);
  ASTORE(1);
  BSTORE(1, pbB);
  sync_ds();
  COMP(1);            // tile 15

  // epilogue: c = sigmoid(i+bi)*tanh(g+bg)*imp -> aggT (swizzled tile layout)
  const int col16 = lane & 15, row4 = (lane >> 4) << 2;
  const float impv = imp[v];
  const int h = h0 + (wh << 4) + col16;
  const float bsi = b_ih[v * 2048 + h] + b_hh[v * 2048 + h];
  const float bsg = b_ih[v * 2048 + 1024 + h] + b_hh[v * 2048 + 1024 + h];
  char* obase = (char*)aggT + ((size_t)v * 8 + (h >> 6)) * 32768;
  const int hc = h & 63;
#pragma unroll
  for (int i = 0; i < 4; ++i)
#pragma unroll
    for (int r = 0; r < 4; ++r) {
      const int m = (wm << 6) + (i << 4) + row4 + r;
      const float ii = acc_i[i][r] + bsi;
      const float gg = acc_g[i][r] + bsg;
      const float c = (1.0f / (1.0f + __expf(-ii))) * tanhf(gg) * impv;
      *(unsigned short*)(obase + (((m << 7) + (hc << 1)) ^ ((m & 7) << 4))) = f2bf(c);
    }
#undef STEP
#undef COMP
#undef ALOAD
#undef ASTORE
#undef BLOAD
#undef BSTORE
}

// ---------------------------------------------------------------------------
// K3: mlp1 split-K GEMM, SPLIT=16 (Kslice=1024 = vars 2s,2s+1), BN=32.
//   Grid 512 (2 blocks/CU). A: aggT tiles via gload_lds dbuf (16 tiles).
//   B: m1w fp32, 1 gldx4/thread depth-2. part bf16.
// ---------------------------------------------------------------------------
__global__ __launch_bounds__(512, 4) void k3_mlp1(
    const unsigned short* __restrict__ aggT,
    const float* __restrict__ Wm,          // [1024][16384]
    unsigned short* __restrict__ part)     // [16][256][1024] bf16
{
  const int bid = blockIdx.x;
  const int chunk = ((bid & 7) << 6) | (bid >> 3);
  const int s = chunk >> 5;                 // 0..15
  const int n0 = (chunk & 31) << 5;         // 0..992

  const int t = threadIdx.x, lane = t & 63, wave = t >> 6;
  const int wm = wave & 3, wn = wave >> 2;  // wn 0..1

  __shared__ __align__(16) unsigned char smem[73728]; // A:2x32K @0, B:2x4K @65536

  const char* Asrc = (const char*)aggT + (size_t)s * 16 * 32768 + wave * 1024 + lane * 16;
  const unsigned aoff = wave * 1024u;

  const int brow = t >> 4;                  // 0..31
  const int bcol = (t & 15) << 2;           // 0..60
  const float* Bsrc = Wm + (size_t)(n0 + brow) * 16384 + (size_t)s * 1024 + bcol;
  const unsigned bwoff = (unsigned)(((brow << 7) + (bcol << 1)) ^ ((brow & 7) << 4));

  f32x4 acc[4] = {};
  f32x4 pbA, pbB;

#define GLA(BUF, KT) do { \
    _Pragma("unroll") for (int _r = 0; _r < 4; ++_r) \
      gload16(Asrc + (KT) * 32768 + _r * 8192, \
              smem + (BUF) * 32768u + aoff + _r * 8192); } while (0)

#define BLOAD(PB, KT) (PB) = gldx4(Bsrc + (KT) * 64)

#define BSTORE(BUF, PB) \
    *(us4*)(smem + 65536u + (BUF) * 4096u + bwoff) = cvt4(PB)

#define COMP(BUF) do { \
    const unsigned char* Ab = smem + (BUF) * 32768u; \
    const unsigned char* Bb = smem + 65536u + (BUF) * 4096u; \
    const int fr = lane & 15, k16 = (lane >> 4) << 4; \
    _Pragma("unroll") for (int kk = 0; kk < 2; ++kk) { \
      short8 a[4], bfr; \
      _Pragma("unroll") for (int i = 0; i < 4; ++i) { \
        const int rw = (wm << 6) + (i << 4) + fr; \
        a[i] = *(const short8*)(Ab + (((rw << 7) + (kk << 6) + k16) ^ ((rw & 7) << 4))); \
      } \
      { const int rw = (wn << 4) + fr; \
        bfr = *(const short8*)(Bb + (((rw << 7) + (kk << 6) + k16) ^ ((rw & 7) << 4))); } \
      _Pragma("unroll") for (int i = 0; i < 4; ++i) \
        acc[i] = __builtin_amdgcn_mfma_f32_16x16x32_bf16(a[i], bfr, acc[i], 0, 0, 0); \
    } } while (0)

  // STEP invariant at entry: in-flight = B(KT+1) (1 load).
#define STEP(CUR, NXT, PBP, PBN, KT) do { \
    GLA(NXT, (KT) + 1);     /* 4 */ \
    BLOAD(PBN, (KT) + 2);   /* 1 */ \
    COMP(CUR); \
    WAITVM(1);   /* drain B(KT+1)+GLA; keep B(KT+2) */ \
    BSTORE(NXT, PBP); \
    sync_ds(); } while (0)

  GLA(0, 0);
  BLOAD(pbA, 0);
  BLOAD(pbB, 1);
  WAITVM(1);
  BSTORE(0, pbA);
  sync_ds();

#pragma unroll
  for (int kt = 0; kt < 14; kt += 2) {
    STEP(0, 1, pbB, pbA, kt);
    STEP(1, 0, pbA, pbB, kt + 1);
  }
  // tail: buf0 holds tile 14; pbB = B(15) in flight
  GLA(1, 15);
  COMP(0);            // tile 14
  WAITVM(0);
  BSTORE(1, pbB);
  sync_ds();
  COMP(1);            // tile 15

  const int col16 = lane & 15, row4 = (lane >> 4) << 2;
  unsigned short* outp = part + (size_t)s * BATCH * 1024;
#pragma unroll
  for (int i = 0; i < 4; ++i)
#pragma unroll
    for (int r = 0; r < 4; ++r)
      outp[(size_t)((wm << 6) + (i << 4) + row4 + r) * 1024
           + n0 + (wn << 4) + col16] = f2bf(acc[i][r]);
#undef STEP
#undef COMP
#undef GLA
#undef BLOAD
#undef BSTORE
}

// ---------------------------------------------------------------------------
// K4: fused head (bf16 partials). One block per batch row, 512 threads,
//     each thread owns 2 n's via one dword read per split.
// ---------------------------------------------------------------------------
__global__ __launch_bounds__(512) void k4_head(
    const unsigned short* __restrict__ part,   // [16][256][1024] bf16
    const float* __restrict__ b1,
    const float* __restrict__ w2,
    const float* __restrict__ b2,
    float* __restrict__ out)
{
  const int b = blockIdx.x;
  const int t = threadIdx.x;          // 0..511
  const int n0 = t << 1;
  float s0 = b1[n0], s1 = b1[n0 + 1];
#pragma unroll
  for (int sp = 0; sp < SPLIT; ++sp) {
    const unsigned u = *(const unsigned*)(part + ((size_t)sp * BATCH + b) * 1024 + n0);
    union { unsigned u; float f; } lo, hi;
    lo.u = u << 16;
    hi.u = u & 0xffff0000u;
    s0 += lo.f;
    s1 += hi.f;
  }
  float accum = fmaxf(s0, 0.0f) * w2[n0] + fmaxf(s1, 0.0f) * w2[n0 + 1];
  __shared__ float red[8];
#pragma unroll
  for (int off = 32; off > 0; off >>= 1)
    accum += __shfl_down(accum, off);
  if ((t & 63) == 0) red[t >> 6] = accum;
  __syncthreads();
  if (t == 0) {
    float r = b2[0];
#pragma unroll
    for (int w = 0; w < 8; ++w) r += red[w];
    out[b] = r;
  }
}

// ---------------------------------------------------------------------------
extern "C" void kernel_launch(void* const* d_in, const int* in_sizes, int n_in,
                              void* d_out, int out_size, void* d_ws, size_t ws_size,
                              hipStream_t stream) {
  const float* inputs = (const float*)d_in[0];
  const float* W_ih   = (const float*)d_in[1];
  // d_in[2] = W_hh: unused (h0 == 0)
  const float* b_ih   = (const float*)d_in[3];
  const float* b_hh   = (const float*)d_in[4];
  const float* imp    = (const float*)d_in[5];
  const float* m1w    = (const float*)d_in[6];
  const float* m1b    = (const float*)d_in[7];
  const float* m2w    = (const float*)d_in[8];
  const float* m2b    = (const float*)d_in[9];
  float* out = (float*)d_out;

  char* ws = (char*)d_ws;
  unsigned short* aggT = (unsigned short*)ws;               // 8 MB tiled bf16
  unsigned short* part = (unsigned short*)(ws + (8u << 20)); // 8 MB bf16

  k1_gates<<<dim3(512), 512, 0, stream>>>(inputs, W_ih, b_ih, b_hh, imp, aggT);
  k3_mlp1 <<<dim3(512), 512, 0, stream>>>(aggT, m1w, part);
  k4_head <<<dim3(256), 512, 0, stream>>>(part, m1b, m2w, m2b, out);
}